// Round 4
// baseline (5275.038 us; speedup 1.0000x reference)
//
#include <hip/hip_runtime.h>
#include <math.h>

#define NN 50000
#define EE 1000000
#define BB 512

__device__ __forceinline__ float sigmoidf_(float x) { return 1.0f / (1.0f + __expf(-x)); }

// ---------------------------------------------------------------------------
// Edge message + scatter-add:  agg[dst] += relu(x[src] + ea @ ew + eb)
// One thread per edge. Weights staged in LDS (broadcast reads).
// (resubmit R3 — prior rounds failed on an unresponsive container)
// ---------------------------------------------------------------------------
template <int C>
__global__ __launch_bounds__(256) void edge_msg_kernel(
    const float* __restrict__ eattr, const float* __restrict__ efeat,
    const int* __restrict__ ei, const float* __restrict__ xin,
    const float* __restrict__ ew, const float* __restrict__ eb,
    float* __restrict__ agg)
{
    __shared__ float w_lds[16 * C + C];
    for (int i = threadIdx.x; i < 16 * C + C; i += 256)
        w_lds[i] = (i < 16 * C) ? ew[i] : eb[i - 16 * C];
    __syncthreads();

    int e = blockIdx.x * 256 + threadIdx.x;
    if (e >= EE) return;

    int src = ei[e];
    int dst = ei[EE + e];

    float a[16];
    {
        const float4* pa = reinterpret_cast<const float4*>(eattr) + (size_t)e * 2;
        const float4* pf = reinterpret_cast<const float4*>(efeat) + (size_t)e * 2;
        float4 v0 = pa[0], v1 = pa[1], v2 = pf[0], v3 = pf[1];
        a[0] = v0.x; a[1] = v0.y; a[2] = v0.z; a[3] = v0.w;
        a[4] = v1.x; a[5] = v1.y; a[6] = v1.z; a[7] = v1.w;
        a[8] = v2.x; a[9] = v2.y; a[10] = v2.z; a[11] = v2.w;
        a[12] = v3.x; a[13] = v3.y; a[14] = v3.z; a[15] = v3.w;
    }

    float acc[C];
    // init: x[src] + bias
    {
        const float4* xb = reinterpret_cast<const float4*>(xin + (size_t)src * C);
        const float4* bb = reinterpret_cast<const float4*>(&w_lds[16 * C]);
#pragma unroll
        for (int c4 = 0; c4 < C / 4; ++c4) {
            float4 xv = xb[c4];
            float4 bv = bb[c4];
            acc[4 * c4 + 0] = xv.x + bv.x;
            acc[4 * c4 + 1] = xv.y + bv.y;
            acc[4 * c4 + 2] = xv.z + bv.z;
            acc[4 * c4 + 3] = xv.w + bv.w;
        }
    }
#pragma unroll
    for (int k = 0; k < 16; ++k) {
        float av = a[k];
        const float4* wr = reinterpret_cast<const float4*>(&w_lds[k * C]);
#pragma unroll
        for (int c4 = 0; c4 < C / 4; ++c4) {
            float4 wv = wr[c4];
            acc[4 * c4 + 0] += av * wv.x;
            acc[4 * c4 + 1] += av * wv.y;
            acc[4 * c4 + 2] += av * wv.z;
            acc[4 * c4 + 3] += av * wv.w;
        }
    }

    float* ar = agg + (size_t)dst * C;
#pragma unroll
    for (int c = 0; c < C; ++c) {
        float m = fmaxf(acc[c], 0.0f);
        unsafeAtomicAdd(ar + c, m);
    }
}

// ---------------------------------------------------------------------------
// Node MLP: out = relu( relu((x+agg) @ w1 + b1) @ w2 + b2 )   [N, CIN] -> [N, 64]
// Wave-per-row, lane = output channel, __shfl broadcasts the input vector.
// ---------------------------------------------------------------------------
template <int CIN>
__global__ __launch_bounds__(256) void node_mlp_kernel(
    const float* __restrict__ xin, const float* __restrict__ agg,
    const float* __restrict__ w1, const float* __restrict__ b1,
    const float* __restrict__ w2, const float* __restrict__ b2,
    float* __restrict__ outp)
{
    __shared__ float w1_lds[CIN * 64];
    __shared__ float w2_lds[64 * 64];
    __shared__ float b_lds[128];
    for (int i = threadIdx.x; i < CIN * 64; i += 256) w1_lds[i] = w1[i];
    for (int i = threadIdx.x; i < 64 * 64; i += 256) w2_lds[i] = w2[i];
    if (threadIdx.x < 64) b_lds[threadIdx.x] = b1[threadIdx.x];
    else if (threadIdx.x < 128) b_lds[threadIdx.x] = b2[threadIdx.x - 64];
    __syncthreads();

    int wave = threadIdx.x >> 6, lane = threadIdx.x & 63;
    int row = blockIdx.x * 4 + wave;
    if (row >= NN) return;

    float in_v = 0.0f;
    if (lane < CIN)
        in_v = xin[(size_t)row * CIN + lane] + agg[(size_t)row * CIN + lane];

    float hid = b_lds[lane];
#pragma unroll
    for (int i = 0; i < CIN; ++i)
        hid += __shfl(in_v, i) * w1_lds[i * 64 + lane];
    hid = fmaxf(hid, 0.0f);

    float o = b_lds[64 + lane];
#pragma unroll
    for (int i = 0; i < 64; ++i)
        o += __shfl(hid, i) * w2_lds[i * 64 + lane];

    outp[(size_t)row * 64 + lane] = fmaxf(o, 0.0f);
}

// ---------------------------------------------------------------------------
// Set2Set (3 steps) + dense head. One block (256 thr = 4 waves) per graph.
// batch is sorted -> binary search the node range. Online softmax.
// ---------------------------------------------------------------------------
__global__ __launch_bounds__(256) void set2set_head_kernel(
    const float* __restrict__ h2, const int* __restrict__ batch,
    const float* __restrict__ wih, const float* __restrict__ bih,
    const float* __restrict__ whh, const float* __restrict__ bhh,
    const float* __restrict__ dw, const float* __restrict__ db,
    const float* __restrict__ ow, const float* __restrict__ ob,
    float* __restrict__ outp)
{
    int b = blockIdx.x;
    int tid = threadIdx.x;
    __shared__ float qstar[128], hh[64], cc[64], gates[256];
    __shared__ float red_m[4], red_s[4], red_r[4][64], zbuf[64];

    // node range for this graph
    int lo = 0, hi = NN;
    while (lo < hi) { int mid = (lo + hi) >> 1; if (batch[mid] < b) lo = mid + 1; else hi = mid; }
    int start = lo;
    hi = NN;
    while (lo < hi) { int mid = (lo + hi) >> 1; if (batch[mid] < b + 1) lo = mid + 1; else hi = mid; }
    int end = lo;

    if (tid < 128) qstar[tid] = 0.0f;
    if (tid < 64) { hh[tid] = 0.0f; cc[tid] = 0.0f; }
    __syncthreads();

    int wave = tid >> 6, lane = tid & 63;

    for (int step = 0; step < 3; ++step) {
        // LSTM gates: one thread per gate element (256)
        float g = bih[tid] + bhh[tid];
        {
            const float* wr = wih + (size_t)tid * 128;
#pragma unroll 4
            for (int k = 0; k < 128; ++k) g += qstar[k] * wr[k];
            const float* hr = whh + (size_t)tid * 64;
#pragma unroll 4
            for (int k = 0; k < 64; ++k) g += hh[k] * hr[k];
        }
        gates[tid] = g;
        __syncthreads();
        if (tid < 64) {
            float gi = gates[tid], gf = gates[64 + tid], gg = gates[128 + tid], go = gates[192 + tid];
            float c = sigmoidf_(gf) * cc[tid] + sigmoidf_(gi) * tanhf(gg);
            cc[tid] = c;
            hh[tid] = sigmoidf_(go) * tanhf(c);
        }
        __syncthreads();

        float r_lane = 0.0f;
        if (end > start) {   // block-uniform condition
            float q = hh[lane];
            // pass 1: online max & denom per wave
            float m = -INFINITY, s = 0.0f;
            for (int n = start + wave; n < end; n += 4) {
                float v = h2[(size_t)n * 64 + lane];
                float p = v * q;
#pragma unroll
                for (int off = 32; off; off >>= 1) p += __shfl_xor(p, off);
                float nm = fmaxf(m, p);
                s = s * __expf(m - nm) + __expf(p - nm);
                m = nm;
            }
            if (lane == 0) { red_m[wave] = m; red_s[wave] = s; }
            __syncthreads();
            float M = fmaxf(fmaxf(red_m[0], red_m[1]), fmaxf(red_m[2], red_m[3]));
            float S = 0.0f;
#pragma unroll
            for (int w = 0; w < 4; ++w) {
                float mm = red_m[w];
                if (mm > -INFINITY) S += red_s[w] * __expf(mm - M);
            }
            // pass 2: weighted sum
            for (int n = start + wave; n < end; n += 4) {
                float v = h2[(size_t)n * 64 + lane];
                float p = v * q;
#pragma unroll
                for (int off = 32; off; off >>= 1) p += __shfl_xor(p, off);
                r_lane += __expf(p - M) / S * v;
            }
        } else {
            __syncthreads();
        }
        red_r[wave][lane] = r_lane;
        __syncthreads();
        if (tid < 64) {
            qstar[tid] = hh[tid];
            qstar[64 + tid] = red_r[0][tid] + red_r[1][tid] + red_r[2][tid] + red_r[3][tid];
        }
        __syncthreads();
    }

    // dense head: z = relu(qstar @ dw + db); out = z @ ow + ob
    if (tid < 64) {
        float z = db[tid];
#pragma unroll 4
        for (int k = 0; k < 128; ++k) z += qstar[k] * dw[k * 64 + tid];
        zbuf[tid] = fmaxf(z, 0.0f);
    }
    __syncthreads();
    if (tid < 64) {
        float t = zbuf[tid] * ow[tid];
#pragma unroll
        for (int off = 32; off; off >>= 1) t += __shfl_xor(t, off);
        if (tid == 0) outp[b] = t + ob[0];
    }
}

// ---------------------------------------------------------------------------
extern "C" void kernel_launch(void* const* d_in, const int* in_sizes, int n_in,
                              void* d_out, int out_size, void* d_ws, size_t ws_size,
                              hipStream_t stream)
{
    const float* x     = (const float*)d_in[0];
    const float* eattr = (const float*)d_in[1];
    const float* efeat = (const float*)d_in[2];
    const int*   ei    = (const int*)d_in[3];
    const int*   batch = (const int*)d_in[4];
    const float* c0_ew = (const float*)d_in[5];  const float* c0_eb = (const float*)d_in[6];
    const float* c0_w1 = (const float*)d_in[7];  const float* c0_b1 = (const float*)d_in[8];
    const float* c0_w2 = (const float*)d_in[9];  const float* c0_b2 = (const float*)d_in[10];
    const float* c1_ew = (const float*)d_in[11]; const float* c1_eb = (const float*)d_in[12];
    const float* c1_w1 = (const float*)d_in[13]; const float* c1_b1 = (const float*)d_in[14];
    const float* c1_w2 = (const float*)d_in[15]; const float* c1_b2 = (const float*)d_in[16];
    const float* wih   = (const float*)d_in[17]; const float* bih   = (const float*)d_in[18];
    const float* whh   = (const float*)d_in[19]; const float* bhh   = (const float*)d_in[20];
    const float* dw    = (const float*)d_in[21]; const float* dbias = (const float*)d_in[22];
    const float* ow    = (const float*)d_in[23]; const float* ob    = (const float*)d_in[24];

    float* out  = (float*)d_out;
    float* ws   = (float*)d_ws;
    float* agg0 = ws;                        // [N,32]
    float* h1   = ws + (size_t)NN * 32;      // [N,64]
    float* agg1 = h1 + (size_t)NN * 64;      // [N,64]
    float* h2   = agg1 + (size_t)NN * 64;    // [N,64]

    hipMemsetAsync(agg0, 0, (size_t)NN * 32 * sizeof(float), stream);
    hipMemsetAsync(agg1, 0, (size_t)NN * 64 * sizeof(float), stream);

    edge_msg_kernel<32><<<(EE + 255) / 256, 256, 0, stream>>>(eattr, efeat, ei, x, c0_ew, c0_eb, agg0);
    node_mlp_kernel<32><<<(NN + 3) / 4, 256, 0, stream>>>(x, agg0, c0_w1, c0_b1, c0_w2, c0_b2, h1);
    edge_msg_kernel<64><<<(EE + 255) / 256, 256, 0, stream>>>(eattr, efeat, ei, h1, c1_ew, c1_eb, agg1);
    node_mlp_kernel<64><<<(NN + 3) / 4, 256, 0, stream>>>(h1, agg1, c1_w1, c1_b1, c1_w2, c1_b2, h2);
    set2set_head_kernel<<<BB, 256, 0, stream>>>(h2, batch, wih, bih, whh, bhh, dw, dbias, ow, ob, out);
}

// Round 5
// 885.666 us; speedup vs baseline: 5.9560x; 5.9560x over previous
//
#include <hip/hip_runtime.h>
#include <math.h>

#define NN 50000
#define EE 1000000
#define BB 512

__device__ __forceinline__ float sigmoidf_(float x) { return 1.0f / (1.0f + __expf(-x)); }

// ---------------------------------------------------------------------------
// CSR build: histogram of dst, exclusive scan, scatter edge ids.
// 2M int atomics total (vs 96M float atomics in the scatter-add version).
// ---------------------------------------------------------------------------
__global__ __launch_bounds__(256) void hist_kernel(const int* __restrict__ ei,
                                                   int* __restrict__ counts)
{
    int e = blockIdx.x * 256 + threadIdx.x;
    if (e < EE) atomicAdd(&counts[ei[EE + e]], 1);
}

__global__ __launch_bounds__(1024) void scan_kernel(const int* __restrict__ counts,
                                                    int* __restrict__ rowptr,
                                                    int* __restrict__ cursor)
{
    __shared__ int s[1024];
    int t = threadIdx.x;
    const int CH = (NN + 1023) / 1024;  // 49
    int lo = t * CH, hi = lo + CH < NN ? lo + CH : NN;
    int sum = 0;
    for (int i = lo; i < hi; ++i) sum += counts[i];
    s[t] = sum;
    __syncthreads();
    for (int off = 1; off < 1024; off <<= 1) {
        int v = (t >= off) ? s[t - off] : 0;
        __syncthreads();
        s[t] += v;
        __syncthreads();
    }
    int base = (t > 0) ? s[t - 1] : 0;
    for (int i = lo; i < hi; ++i) {
        rowptr[i] = base; cursor[i] = base; base += counts[i];
    }
    if (t == 1023) rowptr[NN] = s[1023];
}

__global__ __launch_bounds__(256) void scatter_kernel(const int* __restrict__ ei,
                                                      int* __restrict__ cursor,
                                                      int* __restrict__ perm)
{
    int e = blockIdx.x * 256 + threadIdx.x;
    if (e < EE) {
        int pos = atomicAdd(&cursor[ei[EE + e]], 1);
        perm[pos] = e;
    }
}

// ---------------------------------------------------------------------------
// Fused GINE layer (gather form): one wave per node.
//   agg = sum_{e in in(node)} relu(x[src(e)] + ea[e] @ ew + eb)
//   hout = relu( relu((x[node]+agg) @ w1 + b1) @ w2 + b2 )
// Edge messages recomputed in-register; NO float atomics, no msg buffer.
// CIN=32: two edges per iteration (one per half-wave). CIN=64: 2-unrolled.
// ---------------------------------------------------------------------------
template <int CIN>
__global__ __launch_bounds__(256) void gine_fused_kernel(
    const float* __restrict__ xin, const int* __restrict__ ei,
    const int* __restrict__ perm, const int* __restrict__ rowptr,
    const float* __restrict__ eattr, const float* __restrict__ efeat,
    const float* __restrict__ ew, const float* __restrict__ eb,
    const float* __restrict__ w1, const float* __restrict__ b1,
    const float* __restrict__ w2, const float* __restrict__ b2,
    float* __restrict__ hout)
{
    __shared__ float ew_lds[16 * CIN];
    __shared__ float w1_lds[CIN * 64];
    __shared__ float w2_lds[64 * 64];
    __shared__ float eb_lds[64], b1_lds[64], b2_lds[64];

    for (int i = threadIdx.x; i < 16 * CIN; i += 256) ew_lds[i] = ew[i];
    for (int i = threadIdx.x; i < CIN * 64; i += 256) w1_lds[i] = w1[i];
    for (int i = threadIdx.x; i < 64 * 64; i += 256) w2_lds[i] = w2[i];
    if (threadIdx.x < 64) {
        eb_lds[threadIdx.x] = (threadIdx.x < CIN) ? eb[threadIdx.x] : 0.0f;
        b1_lds[threadIdx.x] = b1[threadIdx.x];
        b2_lds[threadIdx.x] = b2[threadIdx.x];
    }
    __syncthreads();

    int wave = threadIdx.x >> 6, lane = threadIdx.x & 63;
    int node = blockIdx.x * 4 + wave;
    if (node >= NN) return;

    int start = rowptr[node], end = rowptr[node + 1];
    float agg = 0.0f;

    if constexpr (CIN == 32) {
        int half = lane >> 5, l32 = lane & 31;
        int j = start;
        for (; j + 1 < end; j += 2) {
            int e = perm[j + half];
            int src = ei[e];
            float av = (l32 < 8) ? eattr[(size_t)e * 8 + l32]
                     : (l32 < 16) ? efeat[(size_t)e * 8 + l32 - 8] : 0.0f;
            float msg = xin[(size_t)src * 32 + l32] + eb_lds[l32];
#pragma unroll
            for (int k = 0; k < 16; ++k)
                msg += __shfl(av, (half << 5) + k) * ew_lds[k * 32 + l32];
            agg += fmaxf(msg, 0.0f);
        }
        if (j < end) {  // tail: single edge on half 0, half 1 contributes 0
            int e = perm[j];
            int src = ei[e];
            float av = (l32 < 8) ? eattr[(size_t)e * 8 + l32]
                     : (l32 < 16) ? efeat[(size_t)e * 8 + l32 - 8] : 0.0f;
            float msg = xin[(size_t)src * 32 + l32] + eb_lds[l32];
#pragma unroll
            for (int k = 0; k < 16; ++k)
                msg += __shfl(av, (half << 5) + k) * ew_lds[k * 32 + l32];
            agg += (half == 0) ? fmaxf(msg, 0.0f) : 0.0f;
        }
        agg += __shfl_xor(agg, 32);  // combine the two halves
    } else {
        int j = start;
        for (; j + 1 < end; j += 2) {  // 2-unrolled for ILP on the gathers
            int e0 = perm[j], e1 = perm[j + 1];
            int s0 = ei[e0], s1 = ei[e1];
            float av0 = (lane < 8) ? eattr[(size_t)e0 * 8 + lane]
                      : (lane < 16) ? efeat[(size_t)e0 * 8 + lane - 8] : 0.0f;
            float av1 = (lane < 8) ? eattr[(size_t)e1 * 8 + lane]
                      : (lane < 16) ? efeat[(size_t)e1 * 8 + lane - 8] : 0.0f;
            float m0 = xin[(size_t)s0 * 64 + lane] + eb_lds[lane];
            float m1 = xin[(size_t)s1 * 64 + lane] + eb_lds[lane];
#pragma unroll
            for (int k = 0; k < 16; ++k) {
                float w = ew_lds[k * 64 + lane];
                m0 += __shfl(av0, k) * w;
                m1 += __shfl(av1, k) * w;
            }
            agg += fmaxf(m0, 0.0f) + fmaxf(m1, 0.0f);
        }
        if (j < end) {
            int e = perm[j];
            int src = ei[e];
            float av = (lane < 8) ? eattr[(size_t)e * 8 + lane]
                     : (lane < 16) ? efeat[(size_t)e * 8 + lane - 8] : 0.0f;
            float msg = xin[(size_t)src * 64 + lane] + eb_lds[lane];
#pragma unroll
            for (int k = 0; k < 16; ++k)
                msg += __shfl(av, k) * ew_lds[k * 64 + lane];
            agg += fmaxf(msg, 0.0f);
        }
    }

    // node MLP
    float h_in = 0.0f;
    if (lane < CIN) h_in = xin[(size_t)node * CIN + lane] + agg;

    float hid = b1_lds[lane];
#pragma unroll
    for (int i = 0; i < CIN; ++i)
        hid += __shfl(h_in, i) * w1_lds[i * 64 + lane];
    hid = fmaxf(hid, 0.0f);

    float o = b2_lds[lane];
#pragma unroll
    for (int i = 0; i < 64; ++i)
        o += __shfl(hid, i) * w2_lds[i * 64 + lane];

    hout[(size_t)node * 64 + lane] = fmaxf(o, 0.0f);
}

// ---------------------------------------------------------------------------
// Set2Set (3 steps) + dense head. One block (256 thr = 4 waves) per graph.
// ---------------------------------------------------------------------------
__global__ __launch_bounds__(256) void set2set_head_kernel(
    const float* __restrict__ h2, const int* __restrict__ batch,
    const float* __restrict__ wih, const float* __restrict__ bih,
    const float* __restrict__ whh, const float* __restrict__ bhh,
    const float* __restrict__ dw, const float* __restrict__ db,
    const float* __restrict__ ow, const float* __restrict__ ob,
    float* __restrict__ outp)
{
    int b = blockIdx.x;
    int tid = threadIdx.x;
    __shared__ float qstar[128], hh[64], cc[64], gates[256];
    __shared__ float red_m[4], red_s[4], red_r[4][64], zbuf[64];

    int lo = 0, hi = NN;
    while (lo < hi) { int mid = (lo + hi) >> 1; if (batch[mid] < b) lo = mid + 1; else hi = mid; }
    int start = lo;
    hi = NN;
    while (lo < hi) { int mid = (lo + hi) >> 1; if (batch[mid] < b + 1) lo = mid + 1; else hi = mid; }
    int end = lo;

    if (tid < 128) qstar[tid] = 0.0f;
    if (tid < 64) { hh[tid] = 0.0f; cc[tid] = 0.0f; }
    __syncthreads();

    int wave = tid >> 6, lane = tid & 63;

    for (int step = 0; step < 3; ++step) {
        float g = bih[tid] + bhh[tid];
        {
            const float* wr = wih + (size_t)tid * 128;
#pragma unroll 4
            for (int k = 0; k < 128; ++k) g += qstar[k] * wr[k];
            const float* hr = whh + (size_t)tid * 64;
#pragma unroll 4
            for (int k = 0; k < 64; ++k) g += hh[k] * hr[k];
        }
        gates[tid] = g;
        __syncthreads();
        if (tid < 64) {
            float gi = gates[tid], gf = gates[64 + tid], gg = gates[128 + tid], go = gates[192 + tid];
            float c = sigmoidf_(gf) * cc[tid] + sigmoidf_(gi) * tanhf(gg);
            cc[tid] = c;
            hh[tid] = sigmoidf_(go) * tanhf(c);
        }
        __syncthreads();

        float r_lane = 0.0f;
        if (end > start) {
            float q = hh[lane];
            float m = -INFINITY, s = 0.0f;
            for (int n = start + wave; n < end; n += 4) {
                float v = h2[(size_t)n * 64 + lane];
                float p = v * q;
#pragma unroll
                for (int off = 32; off; off >>= 1) p += __shfl_xor(p, off);
                float nm = fmaxf(m, p);
                s = s * __expf(m - nm) + __expf(p - nm);
                m = nm;
            }
            if (lane == 0) { red_m[wave] = m; red_s[wave] = s; }
            __syncthreads();
            float M = fmaxf(fmaxf(red_m[0], red_m[1]), fmaxf(red_m[2], red_m[3]));
            float S = 0.0f;
#pragma unroll
            for (int w = 0; w < 4; ++w) {
                float mm = red_m[w];
                if (mm > -INFINITY) S += red_s[w] * __expf(mm - M);
            }
            for (int n = start + wave; n < end; n += 4) {
                float v = h2[(size_t)n * 64 + lane];
                float p = v * q;
#pragma unroll
                for (int off = 32; off; off >>= 1) p += __shfl_xor(p, off);
                r_lane += __expf(p - M) / S * v;
            }
        } else {
            __syncthreads();
        }
        red_r[wave][lane] = r_lane;
        __syncthreads();
        if (tid < 64) {
            qstar[tid] = hh[tid];
            qstar[64 + tid] = red_r[0][tid] + red_r[1][tid] + red_r[2][tid] + red_r[3][tid];
        }
        __syncthreads();
    }

    if (tid < 64) {
        float z = db[tid];
#pragma unroll 4
        for (int k = 0; k < 128; ++k) z += qstar[k] * dw[k * 64 + tid];
        zbuf[tid] = fmaxf(z, 0.0f);
    }
    __syncthreads();
    if (tid < 64) {
        float t = zbuf[tid] * ow[tid];
#pragma unroll
        for (int off = 32; off; off >>= 1) t += __shfl_xor(t, off);
        if (tid == 0) outp[b] = t + ob[0];
    }
}

// ---------------------------------------------------------------------------
extern "C" void kernel_launch(void* const* d_in, const int* in_sizes, int n_in,
                              void* d_out, int out_size, void* d_ws, size_t ws_size,
                              hipStream_t stream)
{
    const float* x     = (const float*)d_in[0];
    const float* eattr = (const float*)d_in[1];
    const float* efeat = (const float*)d_in[2];
    const int*   ei    = (const int*)d_in[3];
    const int*   batch = (const int*)d_in[4];
    const float* c0_ew = (const float*)d_in[5];  const float* c0_eb = (const float*)d_in[6];
    const float* c0_w1 = (const float*)d_in[7];  const float* c0_b1 = (const float*)d_in[8];
    const float* c0_w2 = (const float*)d_in[9];  const float* c0_b2 = (const float*)d_in[10];
    const float* c1_ew = (const float*)d_in[11]; const float* c1_eb = (const float*)d_in[12];
    const float* c1_w1 = (const float*)d_in[13]; const float* c1_b1 = (const float*)d_in[14];
    const float* c1_w2 = (const float*)d_in[15]; const float* c1_b2 = (const float*)d_in[16];
    const float* wih   = (const float*)d_in[17]; const float* bih   = (const float*)d_in[18];
    const float* whh   = (const float*)d_in[19]; const float* bhh   = (const float*)d_in[20];
    const float* dw    = (const float*)d_in[21]; const float* dbias = (const float*)d_in[22];
    const float* ow    = (const float*)d_in[23]; const float* ob    = (const float*)d_in[24];

    float* out = (float*)d_out;

    int* iws     = (int*)d_ws;
    int* counts  = iws;                  // NN
    int* rowptr  = counts + NN;          // NN+1
    int* cursor  = rowptr + NN + 1;      // NN
    int* perm    = cursor + NN;          // EE
    size_t ioff  = (size_t)NN * 3 + 1 + EE;
    ioff = (ioff + 3) & ~(size_t)3;      // 16B-align the float region
    float* h1 = (float*)(iws + ioff);    // [N,64]
    float* h2 = h1 + (size_t)NN * 64;    // [N,64]

    hipMemsetAsync(counts, 0, (size_t)NN * sizeof(int), stream);

    hist_kernel<<<(EE + 255) / 256, 256, 0, stream>>>(ei, counts);
    scan_kernel<<<1, 1024, 0, stream>>>(counts, rowptr, cursor);
    scatter_kernel<<<(EE + 255) / 256, 256, 0, stream>>>(ei, cursor, perm);

    gine_fused_kernel<32><<<(NN + 3) / 4, 256, 0, stream>>>(
        x, ei, perm, rowptr, eattr, efeat,
        c0_ew, c0_eb, c0_w1, c0_b1, c0_w2, c0_b2, h1);
    gine_fused_kernel<64><<<(NN + 3) / 4, 256, 0, stream>>>(
        h1, ei, perm, rowptr, eattr, efeat,
        c1_ew, c1_eb, c1_w1, c1_b1, c1_w2, c1_b2, h2);

    set2set_head_kernel<<<BB, 256, 0, stream>>>(h2, batch, wih, bih, whh, bhh,
                                                dw, dbias, ow, ob, out);
}

// Round 6
// 744.784 us; speedup vs baseline: 7.0826x; 1.1892x over previous
//
#include <hip/hip_runtime.h>
#include <math.h>

#define NN 50000
#define EE 1000000
#define BB 512

__device__ __forceinline__ float sigmoidf_(float x) { return 1.0f / (1.0f + __expf(-x)); }

// ---------------------------------------------------------------------------
// CSR build: histogram of dst, exclusive scan.
// ---------------------------------------------------------------------------
__global__ __launch_bounds__(256) void hist_kernel(const int* __restrict__ ei,
                                                   int* __restrict__ counts)
{
    int e = blockIdx.x * 256 + threadIdx.x;
    if (e < EE) atomicAdd(&counts[ei[EE + e]], 1);
}

__global__ __launch_bounds__(1024) void scan_kernel(const int* __restrict__ counts,
                                                    int* __restrict__ rowptr,
                                                    int* __restrict__ cursor)
{
    __shared__ int s[1024];
    int t = threadIdx.x;
    const int CH = (NN + 1023) / 1024;
    int lo = t * CH, hi = lo + CH < NN ? lo + CH : NN;
    int sum = 0;
    for (int i = lo; i < hi; ++i) sum += counts[i];
    s[t] = sum;
    __syncthreads();
    for (int off = 1; off < 1024; off <<= 1) {
        int v = (t >= off) ? s[t - off] : 0;
        __syncthreads();
        s[t] += v;
        __syncthreads();
    }
    int base = (t > 0) ? s[t - 1] : 0;
    for (int i = lo; i < hi; ++i) {
        rowptr[i] = base; cursor[i] = base; base += counts[i];
    }
    if (t == 1023) rowptr[NN] = s[1023];
}

// PACKED path: scatter + edge-feature reorder fused. Coalesced reads of
// eattr/efeat (edge order), full-64B-line scattered writes of ea16 + srcp.
__global__ __launch_bounds__(256) void scatter_prep_kernel(
    const int* __restrict__ ei, const float* __restrict__ eattr,
    const float* __restrict__ efeat, int* __restrict__ cursor,
    int* __restrict__ srcp, float* __restrict__ ea16)
{
    int e = blockIdx.x * 256 + threadIdx.x;
    if (e >= EE) return;
    int dst = ei[EE + e];
    int pos = atomicAdd(&cursor[dst], 1);
    srcp[pos] = ei[e];
    const float4* pa = reinterpret_cast<const float4*>(eattr) + (size_t)e * 2;
    const float4* pf = reinterpret_cast<const float4*>(efeat) + (size_t)e * 2;
    float4* o = reinterpret_cast<float4*>(ea16 + (size_t)pos * 16);
    o[0] = pa[0]; o[1] = pa[1]; o[2] = pf[0]; o[3] = pf[1];
}

// Fallback path: scatter edge ids only (R5 layout, ~34 MB ws).
__global__ __launch_bounds__(256) void scatter_kernel(const int* __restrict__ ei,
                                                      int* __restrict__ cursor,
                                                      int* __restrict__ perm)
{
    int e = blockIdx.x * 256 + threadIdx.x;
    if (e < EE) {
        int pos = atomicAdd(&cursor[ei[EE + e]], 1);
        perm[pos] = e;
    }
}

// ---------------------------------------------------------------------------
// Fused GINE layer (gather form): one wave per node.
//   agg  = sum_{e in in(node)} relu(x[src(e)] + ea[e] @ ew + eb)
//   hout = relu( relu((x[node]+agg) @ w1 + b1) @ w2 + b2 )
// PACKED: sequential reads of srcp/ea16 (CSR-ordered); only x[src] is random.
// LDS holds ew + w1 only (w2 read from global, L1-hot) -> 7-8 blocks/CU.
// 4-edge unroll for memory-level parallelism.
// ---------------------------------------------------------------------------
template <int CIN, bool PACKED>
__global__ __launch_bounds__(256) void gine_fused_kernel(
    const float* __restrict__ xin, const int* __restrict__ ei,
    const int* __restrict__ pidx,   // PACKED ? srcp : perm
    const int* __restrict__ rowptr,
    const float* __restrict__ eattr, const float* __restrict__ efeat,
    const float* __restrict__ ea16,
    const float* __restrict__ ew, const float* __restrict__ eb,
    const float* __restrict__ w1, const float* __restrict__ b1,
    const float* __restrict__ w2, const float* __restrict__ b2,
    float* __restrict__ hout)
{
    __shared__ float ew_lds[16 * CIN];
    __shared__ float w1_lds[CIN * 64];
    __shared__ float eb_lds[64], b1_lds[64], b2_lds[64];

    for (int i = threadIdx.x; i < 16 * CIN; i += 256) ew_lds[i] = ew[i];
    for (int i = threadIdx.x; i < CIN * 64; i += 256) w1_lds[i] = w1[i];
    if (threadIdx.x < 64) {
        eb_lds[threadIdx.x] = (threadIdx.x < CIN) ? eb[threadIdx.x] : 0.0f;
        b1_lds[threadIdx.x] = b1[threadIdx.x];
        b2_lds[threadIdx.x] = b2[threadIdx.x];
    }
    __syncthreads();

    int wave = threadIdx.x >> 6, lane = threadIdx.x & 63;
    int node = blockIdx.x * 4 + wave;
    if (node >= NN) return;

    int start = rowptr[node], end = rowptr[node + 1];
    float agg = 0.0f;

    if constexpr (CIN == 32) {
        int half = lane >> 5, l32 = lane & 31;
        float ebv = eb_lds[l32];
        // fetch (src, av) for CSR slot j (this half's lane mapping)
        auto fetch = [&](int j, int& src, float& av) {
            if constexpr (PACKED) {
                src = pidx[j];
                av = (l32 < 16) ? ea16[(size_t)j * 16 + l32] : 0.0f;
            } else {
                int e = pidx[j];
                src = ei[e];
                av = (l32 < 8) ? eattr[(size_t)e * 8 + l32]
                   : (l32 < 16) ? efeat[(size_t)e * 8 + l32 - 8] : 0.0f;
            }
        };
        int j = start;
        for (; j + 3 < end; j += 4) {   // 4 edges: 2 per half-wave
            int s0, s1; float av0, av1;
            fetch(j + half, s0, av0);
            fetch(j + 2 + half, s1, av1);
            float m0 = xin[(size_t)s0 * 32 + l32] + ebv;
            float m1 = xin[(size_t)s1 * 32 + l32] + ebv;
#pragma unroll
            for (int k = 0; k < 16; ++k) {
                float w = ew_lds[k * 32 + l32];
                m0 += __shfl(av0, (half << 5) + k) * w;
                m1 += __shfl(av1, (half << 5) + k) * w;
            }
            agg += fmaxf(m0, 0.0f) + fmaxf(m1, 0.0f);
        }
        for (; j + 1 < end; j += 2) {
            int s0; float av0;
            fetch(j + half, s0, av0);
            float m0 = xin[(size_t)s0 * 32 + l32] + ebv;
#pragma unroll
            for (int k = 0; k < 16; ++k)
                m0 += __shfl(av0, (half << 5) + k) * ew_lds[k * 32 + l32];
            agg += fmaxf(m0, 0.0f);
        }
        if (j < end) {  // single edge, half 0 contributes
            int s0; float av0;
            fetch(j, s0, av0);
            float m0 = xin[(size_t)s0 * 32 + l32] + ebv;
#pragma unroll
            for (int k = 0; k < 16; ++k)
                m0 += __shfl(av0, (half << 5) + k) * ew_lds[k * 32 + l32];
            agg += (half == 0) ? fmaxf(m0, 0.0f) : 0.0f;
        }
        agg += __shfl_xor(agg, 32);
    } else {
        float ebv = eb_lds[lane];
        auto fetch = [&](int j, int& src, float& av) {
            if constexpr (PACKED) {
                src = pidx[j];
                av = (lane < 16) ? ea16[(size_t)j * 16 + lane] : 0.0f;
            } else {
                int e = pidx[j];
                src = ei[e];
                av = (lane < 8) ? eattr[(size_t)e * 8 + lane]
                   : (lane < 16) ? efeat[(size_t)e * 8 + lane - 8] : 0.0f;
            }
        };
        int j = start;
        for (; j + 3 < end; j += 4) {   // 4-edge unroll for MLP
            int s0, s1, s2, s3; float av0, av1, av2, av3;
            fetch(j, s0, av0); fetch(j + 1, s1, av1);
            fetch(j + 2, s2, av2); fetch(j + 3, s3, av3);
            float m0 = xin[(size_t)s0 * 64 + lane] + ebv;
            float m1 = xin[(size_t)s1 * 64 + lane] + ebv;
            float m2 = xin[(size_t)s2 * 64 + lane] + ebv;
            float m3 = xin[(size_t)s3 * 64 + lane] + ebv;
#pragma unroll
            for (int k = 0; k < 16; ++k) {
                float w = ew_lds[k * 64 + lane];
                m0 += __shfl(av0, k) * w;
                m1 += __shfl(av1, k) * w;
                m2 += __shfl(av2, k) * w;
                m3 += __shfl(av3, k) * w;
            }
            agg += fmaxf(m0, 0.0f) + fmaxf(m1, 0.0f)
                 + fmaxf(m2, 0.0f) + fmaxf(m3, 0.0f);
        }
        for (; j < end; ++j) {
            int s0; float av0;
            fetch(j, s0, av0);
            float m0 = xin[(size_t)s0 * 64 + lane] + ebv;
#pragma unroll
            for (int k = 0; k < 16; ++k)
                m0 += __shfl(av0, k) * ew_lds[k * 64 + lane];
            agg += fmaxf(m0, 0.0f);
        }
    }

    // node MLP (w1 from LDS, w2 from global -- broadcast-hot, L1-resident)
    float h_in = 0.0f;
    if (lane < CIN) h_in = xin[(size_t)node * CIN + lane] + agg;

    float hid = b1_lds[lane];
#pragma unroll
    for (int i = 0; i < CIN; ++i)
        hid += __shfl(h_in, i) * w1_lds[i * 64 + lane];
    hid = fmaxf(hid, 0.0f);

    float o = b2_lds[lane];
#pragma unroll
    for (int i = 0; i < 64; ++i)
        o += __shfl(hid, i) * w2[i * 64 + lane];

    hout[(size_t)node * 64 + lane] = fmaxf(o, 0.0f);
}

// ---------------------------------------------------------------------------
// Set2Set (3 steps) + dense head. One block (256 thr = 4 waves) per graph.
// ---------------------------------------------------------------------------
__global__ __launch_bounds__(256) void set2set_head_kernel(
    const float* __restrict__ h2, const int* __restrict__ batch,
    const float* __restrict__ wih, const float* __restrict__ bih,
    const float* __restrict__ whh, const float* __restrict__ bhh,
    const float* __restrict__ dw, const float* __restrict__ db,
    const float* __restrict__ ow, const float* __restrict__ ob,
    float* __restrict__ outp)
{
    int b = blockIdx.x;
    int tid = threadIdx.x;
    __shared__ float qstar[128], hh[64], cc[64], gates[256];
    __shared__ float red_m[4], red_s[4], red_r[4][64], zbuf[64];

    int lo = 0, hi = NN;
    while (lo < hi) { int mid = (lo + hi) >> 1; if (batch[mid] < b) lo = mid + 1; else hi = mid; }
    int start = lo;
    hi = NN;
    while (lo < hi) { int mid = (lo + hi) >> 1; if (batch[mid] < b + 1) lo = mid + 1; else hi = mid; }
    int end = lo;

    if (tid < 128) qstar[tid] = 0.0f;
    if (tid < 64) { hh[tid] = 0.0f; cc[tid] = 0.0f; }
    __syncthreads();

    int wave = tid >> 6, lane = tid & 63;

    for (int step = 0; step < 3; ++step) {
        float g = bih[tid] + bhh[tid];
        {
            const float* wr = wih + (size_t)tid * 128;
#pragma unroll 4
            for (int k = 0; k < 128; ++k) g += qstar[k] * wr[k];
            const float* hr = whh + (size_t)tid * 64;
#pragma unroll 4
            for (int k = 0; k < 64; ++k) g += hh[k] * hr[k];
        }
        gates[tid] = g;
        __syncthreads();
        if (tid < 64) {
            float gi = gates[tid], gf = gates[64 + tid], gg = gates[128 + tid], go = gates[192 + tid];
            float c = sigmoidf_(gf) * cc[tid] + sigmoidf_(gi) * tanhf(gg);
            cc[tid] = c;
            hh[tid] = sigmoidf_(go) * tanhf(c);
        }
        __syncthreads();

        float r_lane = 0.0f;
        if (end > start) {
            float q = hh[lane];
            float m = -INFINITY, s = 0.0f;
            for (int n = start + wave; n < end; n += 4) {
                float v = h2[(size_t)n * 64 + lane];
                float p = v * q;
#pragma unroll
                for (int off = 32; off; off >>= 1) p += __shfl_xor(p, off);
                float nm = fmaxf(m, p);
                s = s * __expf(m - nm) + __expf(p - nm);
                m = nm;
            }
            if (lane == 0) { red_m[wave] = m; red_s[wave] = s; }
            __syncthreads();
            float M = fmaxf(fmaxf(red_m[0], red_m[1]), fmaxf(red_m[2], red_m[3]));
            float S = 0.0f;
#pragma unroll
            for (int w = 0; w < 4; ++w) {
                float mm = red_m[w];
                if (mm > -INFINITY) S += red_s[w] * __expf(mm - M);
            }
            for (int n = start + wave; n < end; n += 4) {
                float v = h2[(size_t)n * 64 + lane];
                float p = v * q;
#pragma unroll
                for (int off = 32; off; off >>= 1) p += __shfl_xor(p, off);
                r_lane += __expf(p - M) / S * v;
            }
        } else {
            __syncthreads();
        }
        red_r[wave][lane] = r_lane;
        __syncthreads();
        if (tid < 64) {
            qstar[tid] = hh[tid];
            qstar[64 + tid] = red_r[0][tid] + red_r[1][tid] + red_r[2][tid] + red_r[3][tid];
        }
        __syncthreads();
    }

    if (tid < 64) {
        float z = db[tid];
#pragma unroll 4
        for (int k = 0; k < 128; ++k) z += qstar[k] * dw[k * 64 + tid];
        zbuf[tid] = fmaxf(z, 0.0f);
    }
    __syncthreads();
    if (tid < 64) {
        float t = zbuf[tid] * ow[tid];
#pragma unroll
        for (int off = 32; off; off >>= 1) t += __shfl_xor(t, off);
        if (tid == 0) outp[b] = t + ob[0];
    }
}

// ---------------------------------------------------------------------------
extern "C" void kernel_launch(void* const* d_in, const int* in_sizes, int n_in,
                              void* d_out, int out_size, void* d_ws, size_t ws_size,
                              hipStream_t stream)
{
    const float* x     = (const float*)d_in[0];
    const float* eattr = (const float*)d_in[1];
    const float* efeat = (const float*)d_in[2];
    const int*   ei    = (const int*)d_in[3];
    const int*   batch = (const int*)d_in[4];
    const float* c0_ew = (const float*)d_in[5];  const float* c0_eb = (const float*)d_in[6];
    const float* c0_w1 = (const float*)d_in[7];  const float* c0_b1 = (const float*)d_in[8];
    const float* c0_w2 = (const float*)d_in[9];  const float* c0_b2 = (const float*)d_in[10];
    const float* c1_ew = (const float*)d_in[11]; const float* c1_eb = (const float*)d_in[12];
    const float* c1_w1 = (const float*)d_in[13]; const float* c1_b1 = (const float*)d_in[14];
    const float* c1_w2 = (const float*)d_in[15]; const float* c1_b2 = (const float*)d_in[16];
    const float* wih   = (const float*)d_in[17]; const float* bih   = (const float*)d_in[18];
    const float* whh   = (const float*)d_in[19]; const float* bhh   = (const float*)d_in[20];
    const float* dw    = (const float*)d_in[21]; const float* dbias = (const float*)d_in[22];
    const float* ow    = (const float*)d_in[23]; const float* ob    = (const float*)d_in[24];

    float* out = (float*)d_out;
    int* iws = (int*)d_ws;

    // PACKED layout: counts NN | rowptr NN+1 | cursor NN | srcp EE | ea16 16E | h1 | h2
    const size_t ioffP = ((size_t)NN * 3 + 1 + EE + 15) & ~(size_t)15;
    const size_t needP = (ioffP + (size_t)EE * 16 + (size_t)NN * 128) * sizeof(int);

    int* counts = iws;
    int* rowptr = counts + NN;
    int* cursor = rowptr + NN + 1;

    hipMemsetAsync(counts, 0, (size_t)NN * sizeof(int), stream);
    hist_kernel<<<(EE + 255) / 256, 256, 0, stream>>>(ei, counts);
    scan_kernel<<<1, 1024, 0, stream>>>(counts, rowptr, cursor);

    if (ws_size >= needP) {
        int*   srcp = cursor + NN;
        float* ea16 = (float*)(iws + ioffP);
        float* h1   = ea16 + (size_t)EE * 16;
        float* h2   = h1 + (size_t)NN * 64;

        scatter_prep_kernel<<<(EE + 255) / 256, 256, 0, stream>>>(
            ei, eattr, efeat, cursor, srcp, ea16);
        gine_fused_kernel<32, true><<<(NN + 3) / 4, 256, 0, stream>>>(
            x, ei, srcp, rowptr, eattr, efeat, ea16,
            c0_ew, c0_eb, c0_w1, c0_b1, c0_w2, c0_b2, h1);
        gine_fused_kernel<64, true><<<(NN + 3) / 4, 256, 0, stream>>>(
            h1, ei, srcp, rowptr, eattr, efeat, ea16,
            c1_ew, c1_eb, c1_w1, c1_b1, c1_w2, c1_b2, h2);
        set2set_head_kernel<<<BB, 256, 0, stream>>>(h2, batch, wih, bih, whh, bhh,
                                                    dw, dbias, ow, ob, out);
    } else {
        // Fallback (R5 layout, ~34 MB): perm indirection, random feature reads.
        int* perm = cursor + NN;
        size_t ioff = ((size_t)NN * 3 + 1 + EE + 15) & ~(size_t)15;
        float* h1 = (float*)(iws + ioff);
        float* h2 = h1 + (size_t)NN * 64;

        scatter_kernel<<<(EE + 255) / 256, 256, 0, stream>>>(ei, cursor, perm);
        gine_fused_kernel<32, false><<<(NN + 3) / 4, 256, 0, stream>>>(
            x, ei, perm, rowptr, eattr, efeat, nullptr,
            c0_ew, c0_eb, c0_w1, c0_b1, c0_w2, c0_b2, h1);
        gine_fused_kernel<64, false><<<(NN + 3) / 4, 256, 0, stream>>>(
            h1, ei, perm, rowptr, eattr, efeat, nullptr,
            c1_ew, c1_eb, c1_w1, c1_b1, c1_w2, c1_b2, h2);
        set2set_head_kernel<<<BB, 256, 0, stream>>>(h2, batch, wih, bih, whh, bhh,
                                                    dw, dbias, ow, ob, out);
    }
}

// Round 7
// 538.156 us; speedup vs baseline: 9.8021x; 1.3840x over previous
//
#include <hip/hip_runtime.h>
#include <math.h>

#define NN 50000
#define EE 1000000
#define BB 512

__device__ __forceinline__ float sigmoidf_(float x) { return 1.0f / (1.0f + __expf(-x)); }

// Wave-uniform loads: force the value into an SGPR so dependent FMAs use the
// scalar operand slot (no ds_bpermute broadcast, no VGPR pressure).
__device__ __forceinline__ float uload(const float* p) {
    return __uint_as_float(__builtin_amdgcn_readfirstlane(__float_as_uint(*p)));
}
__device__ __forceinline__ int uloadi(const int* p) {
    return __builtin_amdgcn_readfirstlane(*p);
}

// ---------------------------------------------------------------------------
// CSR build: histogram of dst, exclusive scan.
// ---------------------------------------------------------------------------
__global__ __launch_bounds__(256) void hist_kernel(const int* __restrict__ ei,
                                                   int* __restrict__ counts)
{
    int e = blockIdx.x * 256 + threadIdx.x;
    if (e < EE) atomicAdd(&counts[ei[EE + e]], 1);
}

__global__ __launch_bounds__(1024) void scan_kernel(const int* __restrict__ counts,
                                                    int* __restrict__ rowptr,
                                                    int* __restrict__ cursor)
{
    __shared__ int s[1024];
    int t = threadIdx.x;
    const int CH = (NN + 1023) / 1024;
    int lo = t * CH, hi = lo + CH < NN ? lo + CH : NN;
    int sum = 0;
    for (int i = lo; i < hi; ++i) sum += counts[i];
    s[t] = sum;
    __syncthreads();
    for (int off = 1; off < 1024; off <<= 1) {
        int v = (t >= off) ? s[t - off] : 0;
        __syncthreads();
        s[t] += v;
        __syncthreads();
    }
    int base = (t > 0) ? s[t - 1] : 0;
    for (int i = lo; i < hi; ++i) {
        rowptr[i] = base; cursor[i] = base; base += counts[i];
    }
    if (t == 1023) rowptr[NN] = s[1023];
}

// PACKED path: scatter + edge-feature reorder fused.
__global__ __launch_bounds__(256) void scatter_prep_kernel(
    const int* __restrict__ ei, const float* __restrict__ eattr,
    const float* __restrict__ efeat, int* __restrict__ cursor,
    int* __restrict__ srcp, float* __restrict__ ea16)
{
    int e = blockIdx.x * 256 + threadIdx.x;
    if (e >= EE) return;
    int dst = ei[EE + e];
    int pos = atomicAdd(&cursor[dst], 1);
    srcp[pos] = ei[e];
    const float4* pa = reinterpret_cast<const float4*>(eattr) + (size_t)e * 2;
    const float4* pf = reinterpret_cast<const float4*>(efeat) + (size_t)e * 2;
    float4* o = reinterpret_cast<float4*>(ea16 + (size_t)pos * 16);
    o[0] = pa[0]; o[1] = pa[1]; o[2] = pf[0]; o[3] = pf[1];
}

// Fallback path: scatter edge ids only.
__global__ __launch_bounds__(256) void scatter_kernel(const int* __restrict__ ei,
                                                      int* __restrict__ cursor,
                                                      int* __restrict__ perm)
{
    int e = blockIdx.x * 256 + threadIdx.x;
    if (e < EE) {
        int pos = atomicAdd(&cursor[ei[EE + e]], 1);
        perm[pos] = e;
    }
}

// ---------------------------------------------------------------------------
// Fused GINE layer, scalarized edge loop. One wave per node.
//   agg  = sum_{e in in(node)} relu(x[src(e)] + ea[e] @ ew + eb)
//   hout = relu( relu((x[node]+agg) @ w1 + b1) @ w2 + b2 )
// Per edge: ~16 v_fmac (SGPR x VGPR) + 1 coalesced 256B gather. No DS ops.
// ---------------------------------------------------------------------------
template <int CIN, bool PACKED>
__global__ __launch_bounds__(256) void gine_fused_kernel(
    const float* __restrict__ xin, const int* __restrict__ ei,
    const int* __restrict__ pidx,   // PACKED ? srcp : perm
    const int* __restrict__ rowptr,
    const float* __restrict__ eattr, const float* __restrict__ efeat,
    const float* __restrict__ ea16,
    const float* __restrict__ ew, const float* __restrict__ eb,
    const float* __restrict__ w1, const float* __restrict__ b1,
    const float* __restrict__ w2, const float* __restrict__ b2,
    float* __restrict__ hout)
{
    __shared__ float w1_lds[CIN * 64];
    for (int i = threadIdx.x; i < CIN * 64; i += 256) w1_lds[i] = w1[i];
    __syncthreads();

    int wave = threadIdx.x >> 6, lane = threadIdx.x & 63;
    int node = blockIdx.x * 4 + wave;
    if (node >= NN) return;

    int ch = lane & (CIN - 1);

    // per-lane edge-linear weight column in registers (coalesced one-time load)
    float wreg[16];
#pragma unroll
    for (int k = 0; k < 16; ++k) wreg[k] = ew[k * CIN + ch];
    float ebv = eb[ch];

    int start = rowptr[node], end = rowptr[node + 1];
    float agg = 0.0f;

    // fetch 16 edge-attr scalars (SGPRs) + src id for a uniform CSR slot
    auto fetch16 = [&](int slot, float* a) -> int {
        if constexpr (PACKED) {
            int src = uloadi(pidx + slot);
            const float* p = ea16 + (size_t)slot * 16;
#pragma unroll
            for (int k = 0; k < 16; ++k) a[k] = uload(p + k);
            return src;
        } else {
            int e = uloadi(pidx + slot);
            int src = uloadi(ei + e);
            const float* pa = eattr + (size_t)e * 8;
            const float* pf = efeat + (size_t)e * 8;
#pragma unroll
            for (int k = 0; k < 8; ++k) { a[k] = uload(pa + k); a[8 + k] = uload(pf + k); }
            return src;
        }
    };

    if constexpr (CIN == 64) {
        int j = start;
        for (; j + 3 < end; j += 4) {
            int jb = __builtin_amdgcn_readfirstlane(j);
            float a0[16], a1[16], a2[16], a3[16];
            int s0 = fetch16(jb, a0);
            int s1 = fetch16(jb + 1, a1);
            int s2 = fetch16(jb + 2, a2);
            int s3 = fetch16(jb + 3, a3);
            float m0 = xin[(size_t)s0 * 64 + lane] + ebv;
            float m1 = xin[(size_t)s1 * 64 + lane] + ebv;
            float m2 = xin[(size_t)s2 * 64 + lane] + ebv;
            float m3 = xin[(size_t)s3 * 64 + lane] + ebv;
#pragma unroll
            for (int k = 0; k < 16; ++k) {
                m0 += a0[k] * wreg[k];
                m1 += a1[k] * wreg[k];
                m2 += a2[k] * wreg[k];
                m3 += a3[k] * wreg[k];
            }
            agg += fmaxf(m0, 0.0f) + fmaxf(m1, 0.0f)
                 + fmaxf(m2, 0.0f) + fmaxf(m3, 0.0f);
        }
        for (; j < end; ++j) {
            int jb = __builtin_amdgcn_readfirstlane(j);
            float a0[16];
            int s0 = fetch16(jb, a0);
            float m0 = xin[(size_t)s0 * 64 + lane] + ebv;
#pragma unroll
            for (int k = 0; k < 16; ++k) m0 += a0[k] * wreg[k];
            agg += fmaxf(m0, 0.0f);
        }
    } else {
        // CIN == 32: two edges per wave (one per half). Both message sums are
        // computed in all lanes from SGPR operands; per-half select at the end.
        int half = lane >> 5;
        int j = start;
        for (; j + 1 < end; j += 2) {
            int jb = __builtin_amdgcn_readfirstlane(j);
            float a0[16], a1[16];
            int s0 = fetch16(jb, a0);
            int s1 = fetch16(jb + 1, a1);
            float xv = xin[(size_t)(half ? s1 : s0) * 32 + ch];
            float m0 = 0.0f, m1 = 0.0f;
#pragma unroll
            for (int k = 0; k < 16; ++k) {
                m0 += a0[k] * wreg[k];
                m1 += a1[k] * wreg[k];
            }
            float m = half ? m1 : m0;
            agg += fmaxf(xv + m + ebv, 0.0f);
        }
        if (j < end) {  // single tail edge: only half 0 contributes
            int jb = __builtin_amdgcn_readfirstlane(j);
            float a0[16];
            int s0 = fetch16(jb, a0);
            float xv = xin[(size_t)s0 * 32 + ch];
            float m0 = 0.0f;
#pragma unroll
            for (int k = 0; k < 16; ++k) m0 += a0[k] * wreg[k];
            agg += (half == 0) ? fmaxf(xv + m0 + ebv, 0.0f) : 0.0f;
        }
        agg += __shfl_xor(agg, 32);  // combine the two halves
    }

    // node MLP (w1 from LDS, w2 from global -- broadcast-hot, L1-resident)
    float h_in = 0.0f;
    if (lane < CIN) h_in = xin[(size_t)node * CIN + lane] + agg;

    float hid = b1[lane];
#pragma unroll
    for (int i = 0; i < CIN; ++i)
        hid += __shfl(h_in, i) * w1_lds[i * 64 + lane];
    hid = fmaxf(hid, 0.0f);

    float o = b2[lane];
#pragma unroll
    for (int i = 0; i < 64; ++i)
        o += __shfl(hid, i) * w2[i * 64 + lane];

    hout[(size_t)node * 64 + lane] = fmaxf(o, 0.0f);
}

// ---------------------------------------------------------------------------
// Set2Set (3 steps) + dense head. One block (256 thr = 4 waves) per graph.
// ---------------------------------------------------------------------------
__global__ __launch_bounds__(256) void set2set_head_kernel(
    const float* __restrict__ h2, const int* __restrict__ batch,
    const float* __restrict__ wih, const float* __restrict__ bih,
    const float* __restrict__ whh, const float* __restrict__ bhh,
    const float* __restrict__ dw, const float* __restrict__ db,
    const float* __restrict__ ow, const float* __restrict__ ob,
    float* __restrict__ outp)
{
    int b = blockIdx.x;
    int tid = threadIdx.x;
    __shared__ float qstar[128], hh[64], cc[64], gates[256];
    __shared__ float red_m[4], red_s[4], red_r[4][64], zbuf[64];

    int lo = 0, hi = NN;
    while (lo < hi) { int mid = (lo + hi) >> 1; if (batch[mid] < b) lo = mid + 1; else hi = mid; }
    int start = lo;
    hi = NN;
    while (lo < hi) { int mid = (lo + hi) >> 1; if (batch[mid] < b + 1) lo = mid + 1; else hi = mid; }
    int end = lo;

    if (tid < 128) qstar[tid] = 0.0f;
    if (tid < 64) { hh[tid] = 0.0f; cc[tid] = 0.0f; }
    __syncthreads();

    int wave = tid >> 6, lane = tid & 63;

    for (int step = 0; step < 3; ++step) {
        float g = bih[tid] + bhh[tid];
        {
            const float* wr = wih + (size_t)tid * 128;
#pragma unroll 4
            for (int k = 0; k < 128; ++k) g += qstar[k] * wr[k];
            const float* hr = whh + (size_t)tid * 64;
#pragma unroll 4
            for (int k = 0; k < 64; ++k) g += hh[k] * hr[k];
        }
        gates[tid] = g;
        __syncthreads();
        if (tid < 64) {
            float gi = gates[tid], gf = gates[64 + tid], gg = gates[128 + tid], go = gates[192 + tid];
            float c = sigmoidf_(gf) * cc[tid] + sigmoidf_(gi) * tanhf(gg);
            cc[tid] = c;
            hh[tid] = sigmoidf_(go) * tanhf(c);
        }
        __syncthreads();

        float r_lane = 0.0f;
        if (end > start) {
            float q = hh[lane];
            float m = -INFINITY, s = 0.0f;
            for (int n = start + wave; n < end; n += 4) {
                float v = h2[(size_t)n * 64 + lane];
                float p = v * q;
#pragma unroll
                for (int off = 32; off; off >>= 1) p += __shfl_xor(p, off);
                float nm = fmaxf(m, p);
                s = s * __expf(m - nm) + __expf(p - nm);
                m = nm;
            }
            if (lane == 0) { red_m[wave] = m; red_s[wave] = s; }
            __syncthreads();
            float M = fmaxf(fmaxf(red_m[0], red_m[1]), fmaxf(red_m[2], red_m[3]));
            float S = 0.0f;
#pragma unroll
            for (int w = 0; w < 4; ++w) {
                float mm = red_m[w];
                if (mm > -INFINITY) S += red_s[w] * __expf(mm - M);
            }
            for (int n = start + wave; n < end; n += 4) {
                float v = h2[(size_t)n * 64 + lane];
                float p = v * q;
#pragma unroll
                for (int off = 32; off; off >>= 1) p += __shfl_xor(p, off);
                r_lane += __expf(p - M) / S * v;
            }
        } else {
            __syncthreads();
        }
        red_r[wave][lane] = r_lane;
        __syncthreads();
        if (tid < 64) {
            qstar[tid] = hh[tid];
            qstar[64 + tid] = red_r[0][tid] + red_r[1][tid] + red_r[2][tid] + red_r[3][tid];
        }
        __syncthreads();
    }

    if (tid < 64) {
        float z = db[tid];
#pragma unroll 4
        for (int k = 0; k < 128; ++k) z += qstar[k] * dw[k * 64 + tid];
        zbuf[tid] = fmaxf(z, 0.0f);
    }
    __syncthreads();
    if (tid < 64) {
        float t = zbuf[tid] * ow[tid];
#pragma unroll
        for (int off = 32; off; off >>= 1) t += __shfl_xor(t, off);
        if (tid == 0) outp[b] = t + ob[0];
    }
}

// ---------------------------------------------------------------------------
extern "C" void kernel_launch(void* const* d_in, const int* in_sizes, int n_in,
                              void* d_out, int out_size, void* d_ws, size_t ws_size,
                              hipStream_t stream)
{
    const float* x     = (const float*)d_in[0];
    const float* eattr = (const float*)d_in[1];
    const float* efeat = (const float*)d_in[2];
    const int*   ei    = (const int*)d_in[3];
    const int*   batch = (const int*)d_in[4];
    const float* c0_ew = (const float*)d_in[5];  const float* c0_eb = (const float*)d_in[6];
    const float* c0_w1 = (const float*)d_in[7];  const float* c0_b1 = (const float*)d_in[8];
    const float* c0_w2 = (const float*)d_in[9];  const float* c0_b2 = (const float*)d_in[10];
    const float* c1_ew = (const float*)d_in[11]; const float* c1_eb = (const float*)d_in[12];
    const float* c1_w1 = (const float*)d_in[13]; const float* c1_b1 = (const float*)d_in[14];
    const float* c1_w2 = (const float*)d_in[15]; const float* c1_b2 = (const float*)d_in[16];
    const float* wih   = (const float*)d_in[17]; const float* bih   = (const float*)d_in[18];
    const float* whh   = (const float*)d_in[19]; const float* bhh   = (const float*)d_in[20];
    const float* dw    = (const float*)d_in[21]; const float* dbias = (const float*)d_in[22];
    const float* ow    = (const float*)d_in[23]; const float* ob    = (const float*)d_in[24];

    float* out = (float*)d_out;
    int* iws = (int*)d_ws;

    // PACKED layout: counts NN | rowptr NN+1 | cursor NN | srcp EE | ea16 16E | h1 | h2
    const size_t ioffP = ((size_t)NN * 3 + 1 + EE + 15) & ~(size_t)15;
    const size_t needP = (ioffP + (size_t)EE * 16 + (size_t)NN * 128) * sizeof(int);

    int* counts = iws;
    int* rowptr = counts + NN;
    int* cursor = rowptr + NN + 1;

    hipMemsetAsync(counts, 0, (size_t)NN * sizeof(int), stream);
    hist_kernel<<<(EE + 255) / 256, 256, 0, stream>>>(ei, counts);
    scan_kernel<<<1, 1024, 0, stream>>>(counts, rowptr, cursor);

    if (ws_size >= needP) {
        int*   srcp = cursor + NN;
        float* ea16 = (float*)(iws + ioffP);
        float* h1   = ea16 + (size_t)EE * 16;
        float* h2   = h1 + (size_t)NN * 64;

        scatter_prep_kernel<<<(EE + 255) / 256, 256, 0, stream>>>(
            ei, eattr, efeat, cursor, srcp, ea16);
        gine_fused_kernel<32, true><<<(NN + 3) / 4, 256, 0, stream>>>(
            x, ei, srcp, rowptr, eattr, efeat, ea16,
            c0_ew, c0_eb, c0_w1, c0_b1, c0_w2, c0_b2, h1);
        gine_fused_kernel<64, true><<<(NN + 3) / 4, 256, 0, stream>>>(
            h1, ei, srcp, rowptr, eattr, efeat, ea16,
            c1_ew, c1_eb, c1_w1, c1_b1, c1_w2, c1_b2, h2);
        set2set_head_kernel<<<BB, 256, 0, stream>>>(h2, batch, wih, bih, whh, bhh,
                                                    dw, dbias, ow, ob, out);
    } else {
        int* perm = cursor + NN;
        size_t ioff = ((size_t)NN * 3 + 1 + EE + 15) & ~(size_t)15;
        float* h1 = (float*)(iws + ioff);
        float* h2 = h1 + (size_t)NN * 64;

        scatter_kernel<<<(EE + 255) / 256, 256, 0, stream>>>(ei, cursor, perm);
        gine_fused_kernel<32, false><<<(NN + 3) / 4, 256, 0, stream>>>(
            x, ei, perm, rowptr, eattr, efeat, nullptr,
            c0_ew, c0_eb, c0_w1, c0_b1, c0_w2, c0_b2, h1);
        gine_fused_kernel<64, false><<<(NN + 3) / 4, 256, 0, stream>>>(
            h1, ei, perm, rowptr, eattr, efeat, nullptr,
            c1_ew, c1_eb, c1_w1, c1_b1, c1_w2, c1_b2, h2);
        set2set_head_kernel<<<BB, 256, 0, stream>>>(h2, batch, wih, bih, whh, bhh,
                                                    dw, dbias, ow, ob, out);
    }
}